// Round 7
// baseline (3364.008 us; speedup 1.0000x reference)
//
#include <hip/hip_runtime.h>
#include <cstdint>

#define T_STEPS 128
#define BATCH 64
#define IDIM 2048
#define HDIM 512
#define G4 2048   // 4*H
#define NCLS 11

typedef __attribute__((ext_vector_type(8))) short bf16x8;
typedef __attribute__((ext_vector_type(4))) float f32x4;

__device__ __forceinline__ unsigned short f2bf(float f) {
    unsigned int u = __builtin_bit_cast(unsigned int, f);
    unsigned int r = u + 0x7FFFu + ((u >> 16) & 1u);   // RNE
    return (unsigned short)(r >> 16);
}
__device__ __forceinline__ float bf2f(unsigned short b) {
    unsigned int u = ((unsigned int)b) << 16;
    return __builtin_bit_cast(float, u);
}
__device__ __forceinline__ float sigm_fast(float x) {
    return 1.f / (1.f + __expf(-x));
}
__device__ __forceinline__ float tanh_fast(float x) {
    float e = __expf(2.f * x);        // inf-safe: x>>0 -> 1, x<<0 -> -1
    return 1.f - 2.f / (e + 1.f);
}

// ---------------------------------------------------------------------------
// Prep: permute gate rows to interleaved order (n' = 4*j + gate), split
// weights into bf16 hi/lo, combine biases, pack h0 into h_pk buffer 0
// (u32 = hi | lo<<16), copy c0 to c_state, zero h_sum.
// orig_row(n') = (n'&3)*512 + (n'>>2)
// ---------------------------------------------------------------------------
__global__ void prep_kernel(const float* __restrict__ W_ih, const float* __restrict__ W_hh,
                            const float* __restrict__ b_ih, const float* __restrict__ b_hh,
                            const float* __restrict__ h0, const float* __restrict__ c0,
                            unsigned short* __restrict__ wih_hi, unsigned short* __restrict__ wih_lo,
                            unsigned short* __restrict__ whh_hi, unsigned short* __restrict__ whh_lo,
                            float* __restrict__ bc,
                            unsigned int* __restrict__ h_pk,
                            float* __restrict__ c_state, float* __restrict__ h_sum) {
    int idx = blockIdx.x * blockDim.x + threadIdx.x;
    int stride = gridDim.x * blockDim.x;
    for (int i = idx; i < G4 * IDIM; i += stride) {
        int np = i / IDIM, k = i - np * IDIM;
        int orig = (np & 3) * HDIM + (np >> 2);
        float f = W_ih[(size_t)orig * IDIM + k];
        unsigned short hi = f2bf(f);
        wih_hi[i] = hi;
        wih_lo[i] = f2bf(f - bf2f(hi));
    }
    for (int i = idx; i < G4 * HDIM; i += stride) {
        int np = i / HDIM, k = i - np * HDIM;
        int orig = (np & 3) * HDIM + (np >> 2);
        float f = W_hh[(size_t)orig * HDIM + k];
        unsigned short hi = f2bf(f);
        whh_hi[i] = hi;
        whh_lo[i] = f2bf(f - bf2f(hi));
    }
    for (int i = idx; i < G4; i += stride) {
        int orig = (i & 3) * HDIM + (i >> 2);
        bc[i] = b_ih[orig] + b_hh[orig];
    }
    for (int i = idx; i < BATCH * HDIM; i += stride) {
        float f = h0[i];
        unsigned short hi = f2bf(f);
        unsigned short lo = f2bf(f - bf2f(hi));
        h_pk[i] = (unsigned)hi | ((unsigned)lo << 16);   // buffer 0
        c_state[i] = c0[i];
        h_sum[i] = 0.f;
    }
}

// ---------------------------------------------------------------------------
// Upfront xg GEMM for rows covering t = 0..(2*mtiles-1).
// xg[.][2048] = x[.][2048] @ Wih''^T + bc   (split-3 bf16 MFMA)
// 128x128 tile, BK=64, 256 threads (4 waves, each a 64x64 quadrant).
// grid = mtiles * 16, mt = bid % mtiles, nt = bid / mtiles.
// ---------------------------------------------------------------------------
__global__ __launch_bounds__(256) void gemm_xg(const float* __restrict__ x,
        const unsigned short* __restrict__ wih_hi, const unsigned short* __restrict__ wih_lo,
        const float* __restrict__ bc, float* __restrict__ xg, int mtiles) {
    __shared__ unsigned short As_hi[128][64];
    __shared__ unsigned short As_lo[128][64];
    __shared__ unsigned short Bs_hi[128][64];
    __shared__ unsigned short Bs_lo[128][64];

    int tid = threadIdx.x;
    int w = tid >> 6, l = tid & 63;
    int lr = l & 15, lc = l >> 4;
    int bid = blockIdx.x;
    int mt = bid % mtiles, nt = bid / mtiles;
    int m0 = mt * 128, n0 = nt * 128;
    int mq = (w >> 1) * 64, nq = (w & 1) * 64;

    f32x4 acc[4][4] = {};

    for (int k0 = 0; k0 < IDIM; k0 += 64) {
        #pragma unroll
        for (int i = 0; i < 8; ++i) {
            int p = i * 256 + tid;            // 0..2047 : 128 rows x 16 chunks
            int r = p >> 4, c4 = p & 15;
            const float4 v = *(const float4*)(x + (size_t)(m0 + r) * IDIM + k0 + c4 * 4);
            unsigned short h0_ = f2bf(v.x), h1_ = f2bf(v.y), h2_ = f2bf(v.z), h3_ = f2bf(v.w);
            unsigned short l0_ = f2bf(v.x - bf2f(h0_));
            unsigned short l1_ = f2bf(v.y - bf2f(h1_));
            unsigned short l2_ = f2bf(v.z - bf2f(h2_));
            unsigned short l3_ = f2bf(v.w - bf2f(h3_));
            uint2 hw, lw;
            hw.x = (unsigned)h0_ | ((unsigned)h1_ << 16);
            hw.y = (unsigned)h2_ | ((unsigned)h3_ << 16);
            lw.x = (unsigned)l0_ | ((unsigned)l1_ << 16);
            lw.y = (unsigned)l2_ | ((unsigned)l3_ << 16);
            *(uint2*)&As_hi[r][c4 * 4] = hw;
            *(uint2*)&As_lo[r][c4 * 4] = lw;
        }
        #pragma unroll
        for (int i = 0; i < 4; ++i) {
            int q = i * 256 + tid;            // 0..1023 : 128 rows x 8 chunks
            int n = q >> 3, c16 = q & 7;
            size_t goff = (size_t)(n0 + n) * IDIM + k0 + c16 * 8;
            *(uint4*)&Bs_hi[n][c16 * 8] = *(const uint4*)(wih_hi + goff);
            *(uint4*)&Bs_lo[n][c16 * 8] = *(const uint4*)(wih_lo + goff);
        }
        __syncthreads();

        #pragma unroll
        for (int ks = 0; ks < 2; ++ks) {
            bf16x8 ah[4], al[4], bh[4], bl[4];
            int col = ks * 32 + lc * 8;
            #pragma unroll
            for (int mb = 0; mb < 4; ++mb) {
                int row = mq + mb * 16 + lr;
                ah[mb] = *(const bf16x8*)&As_hi[row][col];
                al[mb] = *(const bf16x8*)&As_lo[row][col];
            }
            #pragma unroll
            for (int nb = 0; nb < 4; ++nb) {
                int row = nq + nb * 16 + lr;
                bh[nb] = *(const bf16x8*)&Bs_hi[row][col];
                bl[nb] = *(const bf16x8*)&Bs_lo[row][col];
            }
            #pragma unroll
            for (int mb = 0; mb < 4; ++mb)
                #pragma unroll
                for (int nb = 0; nb < 4; ++nb) {
                    acc[mb][nb] = __builtin_amdgcn_mfma_f32_16x16x32_bf16(ah[mb], bh[nb], acc[mb][nb], 0, 0, 0);
                    acc[mb][nb] = __builtin_amdgcn_mfma_f32_16x16x32_bf16(ah[mb], bl[nb], acc[mb][nb], 0, 0, 0);
                    acc[mb][nb] = __builtin_amdgcn_mfma_f32_16x16x32_bf16(al[mb], bh[nb], acc[mb][nb], 0, 0, 0);
                }
        }
        __syncthreads();
    }

    #pragma unroll
    for (int mb = 0; mb < 4; ++mb) {
        #pragma unroll
        for (int nb = 0; nb < 4; ++nb) {
            int col = n0 + nq + nb * 16 + lr;
            float bias = bc[col];
            #pragma unroll
            for (int r = 0; r < 4; ++r) {
                int row = m0 + mq + mb * 16 + lc * 4 + r;
                xg[(size_t)row * G4 + col] = acc[mb][nb][r] + bias;
            }
        }
    }
}

// ---------------------------------------------------------------------------
// Fused step kernel, grid = 192 blocks:
//   blocks 0..63   : LSTM recurrence for step t (as R6; launch boundary = sync)
//   blocks 64..191 : background xg GEMM K-slices for FUTURE steps.
//       bg = bid-64; cb = bg&15 (col-block of 128), s = bg>>4 (K-slice of 256)
//       row-block rb = t + 2 + s (64 rows = one future step's xg rows).
//       Slice s of (rb,cb) runs at dispatch t = rb-2-s, so the 8 slices of a
//       row-block land in 8 distinct earlier dispatches (stream-serialized,
//       race-free read-modify-write). s==7 (earliest) writes bias+partial;
//       s<7 accumulate. rb<10 precomputed by gemm_xg; guard 10<=rb<=127.
// ---------------------------------------------------------------------------
__global__ __launch_bounds__(256) void lstm_step(
        const unsigned short* __restrict__ whh_hi, const unsigned short* __restrict__ whh_lo,
        const float* __restrict__ x,
        const unsigned short* __restrict__ wih_hi, const unsigned short* __restrict__ wih_lo,
        const float* __restrict__ bc,
        float* __restrict__ xg,
        const float* __restrict__ mask_h, const float* __restrict__ mask_c,
        unsigned int* __restrict__ h_pk,
        float* __restrict__ c_state, float* __restrict__ h_sum,
        int t) {
    __shared__ __align__(16) char smem[49152];

    int tid = threadIdx.x;
    int w = tid >> 6, l = tid & 63;
    int lr = l & 15, lc = l >> 4;

    if (blockIdx.x < 64) {
        // ---------------- recurrence block ----------------
        float (*red)[64][32] = (float(*)[64][32])smem;    // 32 KB
        int g = blockIdx.x;
        int cur = (t & 1) * (BATCH * HDIM);
        int nxt = ((t + 1) & 1) * (BATCH * HDIM);

        bf16x8 bh[2][4], bl[2][4];
        #pragma unroll
        for (int nb = 0; nb < 2; ++nb)
            #pragma unroll
            for (int ks = 0; ks < 4; ++ks) {
                int n = g * 32 + nb * 16 + lr;
                int k = w * 128 + ks * 32 + lc * 8;
                bh[nb][ks] = *(const bf16x8*)(whh_hi + (size_t)n * HDIM + k);
                bl[nb][ks] = *(const bf16x8*)(whh_lo + (size_t)n * HDIM + k);
            }

        f32x4 acc[4][2] = {};
        #pragma unroll
        for (int ks = 0; ks < 4; ++ks) {
            int k = w * 128 + ks * 32 + lc * 8;
            #pragma unroll
            for (int mb = 0; mb < 4; ++mb) {
                int row = mb * 16 + lr;
                const unsigned long long* pq = (const unsigned long long*)(h_pk + cur + row * HDIM + k);
                unsigned long long q0 = pq[0], q1 = pq[1], q2 = pq[2], q3 = pq[3];
                union { unsigned int d[4]; bf16x8 v; } ahu, alu;
                {
                    unsigned p0 = (unsigned)q0, p1 = (unsigned)(q0 >> 32);
                    ahu.d[0] = __builtin_amdgcn_perm(p1, p0, 0x05040100u);
                    alu.d[0] = __builtin_amdgcn_perm(p1, p0, 0x07060302u);
                }
                {
                    unsigned p0 = (unsigned)q1, p1 = (unsigned)(q1 >> 32);
                    ahu.d[1] = __builtin_amdgcn_perm(p1, p0, 0x05040100u);
                    alu.d[1] = __builtin_amdgcn_perm(p1, p0, 0x07060302u);
                }
                {
                    unsigned p0 = (unsigned)q2, p1 = (unsigned)(q2 >> 32);
                    ahu.d[2] = __builtin_amdgcn_perm(p1, p0, 0x05040100u);
                    alu.d[2] = __builtin_amdgcn_perm(p1, p0, 0x07060302u);
                }
                {
                    unsigned p0 = (unsigned)q3, p1 = (unsigned)(q3 >> 32);
                    ahu.d[3] = __builtin_amdgcn_perm(p1, p0, 0x05040100u);
                    alu.d[3] = __builtin_amdgcn_perm(p1, p0, 0x07060302u);
                }
                bf16x8 ah = ahu.v, al = alu.v;
                #pragma unroll
                for (int nb = 0; nb < 2; ++nb) {
                    acc[mb][nb] = __builtin_amdgcn_mfma_f32_16x16x32_bf16(ah, bh[nb][ks], acc[mb][nb], 0, 0, 0);
                    acc[mb][nb] = __builtin_amdgcn_mfma_f32_16x16x32_bf16(ah, bl[nb][ks], acc[mb][nb], 0, 0, 0);
                    acc[mb][nb] = __builtin_amdgcn_mfma_f32_16x16x32_bf16(al, bh[nb][ks], acc[mb][nb], 0, 0, 0);
                }
            }
        }
        #pragma unroll
        for (int mb = 0; mb < 4; ++mb)
            #pragma unroll
            for (int nb = 0; nb < 2; ++nb)
                #pragma unroll
                for (int r = 0; r < 4; ++r)
                    red[w][mb * 16 + lc * 4 + r][nb * 16 + lr] = acc[mb][nb][r];
        __syncthreads();

        int b0_ = tid >> 3, jl0 = tid & 7, jg0 = g * 8 + jl0;
        int b1_ = (tid + 256) >> 3, jl1 = tid & 7, jg1 = g * 8 + jl1;
        #pragma unroll
        for (int e = 0; e < 2; ++e) {
            int b  = e ? b1_ : b0_;
            int jl = e ? jl1 : jl0;
            int jg = e ? jg1 : jg0;
            int nb4 = jl * 4;
            float gi = red[0][b][nb4 + 0] + red[1][b][nb4 + 0] + red[2][b][nb4 + 0] + red[3][b][nb4 + 0];
            float gf = red[0][b][nb4 + 1] + red[1][b][nb4 + 1] + red[2][b][nb4 + 1] + red[3][b][nb4 + 1];
            float gg = red[0][b][nb4 + 2] + red[1][b][nb4 + 2] + red[2][b][nb4 + 2] + red[3][b][nb4 + 2];
            float go = red[0][b][nb4 + 3] + red[1][b][nb4 + 3] + red[2][b][nb4 + 3] + red[3][b][nb4 + 3];
            const float4 xgv = *(const float4*)(xg + (size_t)(t * BATCH + b) * G4 + g * 32 + nb4);
            gi += xgv.x; gf += xgv.y; gg += xgv.z; go += xgv.w;
            size_t sidx = (size_t)b * HDIM + jg;
            size_t midx = (size_t)(t * BATCH + b) * HDIM + jg;
            float c_reg = c_state[sidx];
            float i_s = sigm_fast(gi);
            float f_s = sigm_fast(gf);
            float o_s = sigm_fast(go);
            float c_new = f_s * c_reg + i_s * tanh_fast(gg);
            float h_new = o_s * tanh_fast(c_new);
            h_new *= mask_h[midx];
            c_new *= mask_c[midx];
            c_state[sidx] = c_new;
            h_sum[sidx] += h_new;
            unsigned short hh = f2bf(h_new);
            unsigned short hl = f2bf(h_new - bf2f(hh));
            h_pk[nxt + sidx] = (unsigned)hh | ((unsigned)hl << 16);
        }
    } else {
        // ---------------- background xg GEMM slice ----------------
        int bg = blockIdx.x - 64;
        int cb = bg & 15;          // col-block: cols [cb*128, cb*128+128)
        int s  = bg >> 4;          // K-slice:  k in [s*256, s*256+256)
        int rb = t + 2 + s;        // future step whose xg rows we build
        if (rb < 10 || rb > 127) return;

        unsigned short (*As_hi)[64] = (unsigned short(*)[64])(smem);          //  8 KB
        unsigned short (*As_lo)[64] = (unsigned short(*)[64])(smem + 8192);   //  8 KB
        unsigned short (*Bs_hi)[64] = (unsigned short(*)[64])(smem + 16384);  // 16 KB
        unsigned short (*Bs_lo)[64] = (unsigned short(*)[64])(smem + 32768);  // 16 KB

        int m0 = rb * 64;          // 64 rows (one step's batch rows)
        int n0 = cb * 128;
        int nq = w * 32;           // wave's 32-col strip

        f32x4 acc[4][2] = {};

        for (int kc = 0; kc < 4; ++kc) {
            int k0 = s * 256 + kc * 64;
            // stage A: 64 rows x 64 k, f32 -> bf16 hi/lo  (1024 float4)
            #pragma unroll
            for (int i = 0; i < 4; ++i) {
                int p = i * 256 + tid;        // 0..1023: r = p>>4 (64 rows), c4 = p&15
                int r = p >> 4, c4 = p & 15;
                const float4 v = *(const float4*)(x + (size_t)(m0 + r) * IDIM + k0 + c4 * 4);
                unsigned short h0_ = f2bf(v.x), h1_ = f2bf(v.y), h2_ = f2bf(v.z), h3_ = f2bf(v.w);
                unsigned short l0_ = f2bf(v.x - bf2f(h0_));
                unsigned short l1_ = f2bf(v.y - bf2f(h1_));
                unsigned short l2_ = f2bf(v.z - bf2f(h2_));
                unsigned short l3_ = f2bf(v.w - bf2f(h3_));
                uint2 hw, lw;
                hw.x = (unsigned)h0_ | ((unsigned)h1_ << 16);
                hw.y = (unsigned)h2_ | ((unsigned)h3_ << 16);
                lw.x = (unsigned)l0_ | ((unsigned)l1_ << 16);
                lw.y = (unsigned)l2_ | ((unsigned)l3_ << 16);
                *(uint2*)&As_hi[r][c4 * 4] = hw;
                *(uint2*)&As_lo[r][c4 * 4] = lw;
            }
            // stage B: 128 gate-cols x 64 k (1024 uint4 per array)
            #pragma unroll
            for (int i = 0; i < 4; ++i) {
                int q = i * 256 + tid;        // n = q>>3 (128 rows), c16 = q&7
                int n = q >> 3, c16 = q & 7;
                size_t goff = (size_t)(n0 + n) * IDIM + k0 + c16 * 8;
                *(uint4*)&Bs_hi[n][c16 * 8] = *(const uint4*)(wih_hi + goff);
                *(uint4*)&Bs_lo[n][c16 * 8] = *(const uint4*)(wih_lo + goff);
            }
            __syncthreads();

            #pragma unroll
            for (int ks = 0; ks < 2; ++ks) {
                int col = ks * 32 + lc * 8;
                bf16x8 ah[4], al[4], bhh[2], bll[2];
                #pragma unroll
                for (int mb = 0; mb < 4; ++mb) {
                    int row = mb * 16 + lr;
                    ah[mb] = *(const bf16x8*)&As_hi[row][col];
                    al[mb] = *(const bf16x8*)&As_lo[row][col];
                }
                #pragma unroll
                for (int nb = 0; nb < 2; ++nb) {
                    int row = nq + nb * 16 + lr;
                    bhh[nb] = *(const bf16x8*)&Bs_hi[row][col];
                    bll[nb] = *(const bf16x8*)&Bs_lo[row][col];
                }
                #pragma unroll
                for (int mb = 0; mb < 4; ++mb)
                    #pragma unroll
                    for (int nb = 0; nb < 2; ++nb) {
                        acc[mb][nb] = __builtin_amdgcn_mfma_f32_16x16x32_bf16(ah[mb], bhh[nb], acc[mb][nb], 0, 0, 0);
                        acc[mb][nb] = __builtin_amdgcn_mfma_f32_16x16x32_bf16(ah[mb], bll[nb], acc[mb][nb], 0, 0, 0);
                        acc[mb][nb] = __builtin_amdgcn_mfma_f32_16x16x32_bf16(al[mb], bhh[nb], acc[mb][nb], 0, 0, 0);
                    }
            }
            __syncthreads();
        }

        // epilogue: slice 7 initializes with bias, others accumulate
        #pragma unroll
        for (int mb = 0; mb < 4; ++mb) {
            #pragma unroll
            for (int nb = 0; nb < 2; ++nb) {
                int col = n0 + nq + nb * 16 + lr;
                #pragma unroll
                for (int r = 0; r < 4; ++r) {
                    int row = m0 + mb * 16 + lc * 4 + r;
                    size_t off = (size_t)row * G4 + col;
                    if (s == 7) xg[off] = bc[col] + acc[mb][nb][r];
                    else        xg[off] += acc[mb][nb][r];
                }
            }
        }
    }
}

// ---------------------------------------------------------------------------
// Projection: WG g handles batch b = g -> out[g*11 + cl]
// ---------------------------------------------------------------------------
__global__ __launch_bounds__(256) void proj_kernel(
        const float* __restrict__ h_sum,
        const float* __restrict__ W_out, const float* __restrict__ b_out,
        float* __restrict__ out) {
    __shared__ float rbuf[NCLS * 256];
    int g = blockIdx.x, tid = threadIdx.x;
    float part[NCLS];
    #pragma unroll
    for (int cl = 0; cl < NCLS; ++cl) part[cl] = 0.f;
    for (int j = tid; j < HDIM; j += 256) {
        float hv = h_sum[g * HDIM + j] * (1.f / T_STEPS);
        #pragma unroll
        for (int cl = 0; cl < NCLS; ++cl)
            part[cl] += hv * W_out[cl * HDIM + j];
    }
    #pragma unroll
    for (int cl = 0; cl < NCLS; ++cl) rbuf[cl * 256 + tid] = part[cl];
    __syncthreads();
    if (tid < NCLS) {
        float s = b_out[tid];
        for (int i = 0; i < 256; ++i) s += rbuf[tid * 256 + i];
        out[g * NCLS + tid] = s;
    }
}

// ---------------------------------------------------------------------------
extern "C" void kernel_launch(void* const* d_in, const int* in_sizes, int n_in,
                              void* d_out, int out_size, void* d_ws, size_t ws_size,
                              hipStream_t stream) {
    const float* x      = (const float*)d_in[0];
    const float* h0     = (const float*)d_in[1];
    const float* c0     = (const float*)d_in[2];
    const float* W_ih   = (const float*)d_in[3];
    const float* W_hh   = (const float*)d_in[4];
    const float* b_ih   = (const float*)d_in[5];
    const float* b_hh   = (const float*)d_in[6];
    const float* W_out  = (const float*)d_in[7];
    const float* b_out  = (const float*)d_in[8];
    const float* mask_h = (const float*)d_in[9];
    const float* mask_c = (const float*)d_in[10];
    float* out = (float*)d_out;

    char* ws = (char*)d_ws;
    float*          xg      = (float*)(ws + 0);                  // 67,108,864 B
    unsigned short* wih_hi  = (unsigned short*)(ws + 67108864);  // 8,388,608
    unsigned short* wih_lo  = (unsigned short*)(ws + 75497472);  // 8,388,608
    unsigned short* whh_hi  = (unsigned short*)(ws + 83886080);  // 2,097,152
    unsigned short* whh_lo  = (unsigned short*)(ws + 85983232);  // 2,097,152
    float*          bc      = (float*)(ws + 88080384);           // 8,192
    unsigned int*   h_pk    = (unsigned int*)(ws + 88088576);    // 262,144 (2 bufs)
    float*          c_state = (float*)(ws + 88350720);           // 131,072
    float*          h_sum   = (float*)(ws + 88481792);           // 131,072

    prep_kernel<<<8192, 256, 0, stream>>>(W_ih, W_hh, b_ih, b_hh, h0, c0,
                                          wih_hi, wih_lo, whh_hi, whh_lo, bc,
                                          h_pk, c_state, h_sum);
    // upfront xg only for t = 0..9 (rows 0..639 -> 5 M-tiles x 16 N-tiles)
    gemm_xg<<<80, 256, 0, stream>>>(x, wih_hi, wih_lo, bc, xg, 5);

    for (int t = 0; t < T_STEPS; ++t)
        lstm_step<<<192, 256, 0, stream>>>(whh_hi, whh_lo,
                                           x, wih_hi, wih_lo, bc, xg,
                                           mask_h, mask_c,
                                           h_pk, c_state, h_sum, t);

    proj_kernel<<<64, 256, 0, stream>>>(h_sum, W_out, b_out, out);
}

// Round 10
// 1538.213 us; speedup vs baseline: 2.1870x; 2.1870x over previous
//
#include <hip/hip_runtime.h>
#include <cstdint>

#define T_STEPS 128
#define BATCH 64
#define IDIM 2048
#define HDIM 512
#define G4 2048   // 4*H
#define NCLS 11

typedef __attribute__((ext_vector_type(8))) short bf16x8;
typedef __attribute__((ext_vector_type(4))) float f32x4;

__device__ __forceinline__ unsigned short f2bf(float f) {
    unsigned int u = __builtin_bit_cast(unsigned int, f);
    unsigned int r = u + 0x7FFFu + ((u >> 16) & 1u);   // RNE
    return (unsigned short)(r >> 16);
}
__device__ __forceinline__ float bf2f(unsigned short b) {
    unsigned int u = ((unsigned int)b) << 16;
    return __builtin_bit_cast(float, u);
}
__device__ __forceinline__ float sigm_fast(float x) {
    return 1.f / (1.f + __expf(-x));
}
__device__ __forceinline__ float tanh_fast(float x) {
    float e = __expf(2.f * x);        // inf-safe: x>>0 -> 1, x<<0 -> -1
    return 1.f - 2.f / (e + 1.f);
}

// ---------------------------------------------------------------------------
// Prep: permute gate rows to interleaved order (n' = 4*j + gate), split
// weights into bf16 hi/lo (RNE), combine biases, pack h0 into h_pk buffer 0
// (u32 = hi | lo<<16), copy c0 to c_state, zero h_sum.
// orig_row(n') = (n'&3)*512 + (n'>>2)
// ---------------------------------------------------------------------------
__global__ void prep_kernel(const float* __restrict__ W_ih, const float* __restrict__ W_hh,
                            const float* __restrict__ b_ih, const float* __restrict__ b_hh,
                            const float* __restrict__ h0, const float* __restrict__ c0,
                            unsigned short* __restrict__ wih_hi, unsigned short* __restrict__ wih_lo,
                            unsigned short* __restrict__ whh_hi, unsigned short* __restrict__ whh_lo,
                            float* __restrict__ bc,
                            unsigned int* __restrict__ h_pk,
                            float* __restrict__ c_state, float* __restrict__ h_sum) {
    int idx = blockIdx.x * blockDim.x + threadIdx.x;
    int stride = gridDim.x * blockDim.x;
    for (int i = idx; i < G4 * IDIM; i += stride) {
        int np = i / IDIM, k = i - np * IDIM;
        int orig = (np & 3) * HDIM + (np >> 2);
        float f = W_ih[(size_t)orig * IDIM + k];
        unsigned short hi = f2bf(f);
        wih_hi[i] = hi;
        wih_lo[i] = f2bf(f - bf2f(hi));
    }
    for (int i = idx; i < G4 * HDIM; i += stride) {
        int np = i / HDIM, k = i - np * HDIM;
        int orig = (np & 3) * HDIM + (np >> 2);
        float f = W_hh[(size_t)orig * HDIM + k];
        unsigned short hi = f2bf(f);
        whh_hi[i] = hi;
        whh_lo[i] = f2bf(f - bf2f(hi));
    }
    for (int i = idx; i < G4; i += stride) {
        int orig = (i & 3) * HDIM + (i >> 2);
        bc[i] = b_ih[orig] + b_hh[orig];
    }
    for (int i = idx; i < BATCH * HDIM; i += stride) {
        float f = h0[i];
        unsigned short hi = f2bf(f);
        unsigned short lo = f2bf(f - bf2f(hi));
        h_pk[i] = (unsigned)hi | ((unsigned)lo << 16);   // buffer 0
        c_state[i] = c0[i];
        h_sum[i] = 0.f;
    }
}

// ---------------------------------------------------------------------------
// xg GEMM: xg[8192][2048] = x[8192][2048] @ Wih''^T + bc   (split-3 bf16 MFMA)
// 128x128 tile, BK=64, 256 threads (4 waves, each a 64x64 quadrant).
// R10 changes vs R6:
//  - LDS XOR swizzle (16B unit ^= row&7) on BOTH ds_write (staging) and
//    ds_read (fragments): kills the 16-way bank conflict of 128B rows.
//  - A staged via TRUNCATION split: hi = top16(f) (v_perm), lo = top16(f-hi)
//    (exact residual absorbs the truncation error; dropped term ~2^-16).
// ---------------------------------------------------------------------------
__global__ __launch_bounds__(256) void gemm_xg(const float* __restrict__ x,
        const unsigned short* __restrict__ wih_hi, const unsigned short* __restrict__ wih_lo,
        const float* __restrict__ bc, float* __restrict__ xg) {
    __shared__ unsigned short As_hi[128][64];
    __shared__ unsigned short As_lo[128][64];
    __shared__ unsigned short Bs_hi[128][64];
    __shared__ unsigned short Bs_lo[128][64];

    int tid = threadIdx.x;
    int w = tid >> 6, l = tid & 63;
    int lr = l & 15, lc = l >> 4;
    int bid = blockIdx.x;
    int mt = bid & 63, nt = bid >> 6;       // 64 M-tiles x 16 N-tiles
    int m0 = mt * 128, n0 = nt * 128;
    int mq = (w >> 1) * 64, nq = (w & 1) * 64;

    f32x4 acc[4][4] = {};

    for (int k0 = 0; k0 < IDIM; k0 += 64) {
        // stage A: f32 -> bf16 hi/lo via trunc-split, swizzled writes
        #pragma unroll
        for (int i = 0; i < 8; ++i) {
            int p = i * 256 + tid;            // 0..2047 : 128 rows x 16 float4
            int r = p >> 4, c4 = p & 15;
            const float4 v = *(const float4*)(x + (size_t)(m0 + r) * IDIM + k0 + c4 * 4);
            unsigned ux = __builtin_bit_cast(unsigned, v.x);
            unsigned uy = __builtin_bit_cast(unsigned, v.y);
            unsigned uz = __builtin_bit_cast(unsigned, v.z);
            unsigned uw = __builtin_bit_cast(unsigned, v.w);
            float rx = v.x - __builtin_bit_cast(float, ux & 0xFFFF0000u);
            float ry = v.y - __builtin_bit_cast(float, uy & 0xFFFF0000u);
            float rz = v.z - __builtin_bit_cast(float, uz & 0xFFFF0000u);
            float rw = v.w - __builtin_bit_cast(float, uw & 0xFFFF0000u);
            uint2 hw, lw;
            hw.x = __builtin_amdgcn_perm(uy, ux, 0x07060302u);   // [hi16(x), hi16(y)]
            hw.y = __builtin_amdgcn_perm(uw, uz, 0x07060302u);
            lw.x = __builtin_amdgcn_perm(__builtin_bit_cast(unsigned, ry),
                                         __builtin_bit_cast(unsigned, rx), 0x07060302u);
            lw.y = __builtin_amdgcn_perm(__builtin_bit_cast(unsigned, rw),
                                         __builtin_bit_cast(unsigned, rz), 0x07060302u);
            int off = (((c4 >> 1) ^ (r & 7)) * 16) + (c4 & 1) * 8;   // swizzled byte off
            *(uint2*)((char*)&As_hi[r][0] + off) = hw;
            *(uint2*)((char*)&As_lo[r][0] + off) = lw;
        }
        // stage B: bf16 copy (W'' is [n'][k], k contiguous), swizzled writes
        #pragma unroll
        for (int i = 0; i < 4; ++i) {
            int q = i * 256 + tid;            // 0..1023 : 128 rows x 8 16B-chunks
            int n = q >> 3, c16 = q & 7;
            size_t goff = (size_t)(n0 + n) * IDIM + k0 + c16 * 8;
            int off = (c16 ^ (n & 7)) * 16;
            *(uint4*)((char*)&Bs_hi[n][0] + off) = *(const uint4*)(wih_hi + goff);
            *(uint4*)((char*)&Bs_lo[n][0] + off) = *(const uint4*)(wih_lo + goff);
        }
        __syncthreads();

        #pragma unroll
        for (int ks = 0; ks < 2; ++ks) {
            bf16x8 ah[4], al[4], bh[4], bl[4];
            int u0 = ks * 4 + lc;             // logical 16B unit 0..7
            #pragma unroll
            for (int mb = 0; mb < 4; ++mb) {
                int row = mq + mb * 16 + lr;
                int off = (u0 ^ (row & 7)) * 16;
                ah[mb] = *(const bf16x8*)((const char*)&As_hi[row][0] + off);
                al[mb] = *(const bf16x8*)((const char*)&As_lo[row][0] + off);
            }
            #pragma unroll
            for (int nb = 0; nb < 4; ++nb) {
                int row = nq + nb * 16 + lr;
                int off = (u0 ^ (row & 7)) * 16;
                bh[nb] = *(const bf16x8*)((const char*)&Bs_hi[row][0] + off);
                bl[nb] = *(const bf16x8*)((const char*)&Bs_lo[row][0] + off);
            }
            #pragma unroll
            for (int mb = 0; mb < 4; ++mb)
                #pragma unroll
                for (int nb = 0; nb < 4; ++nb) {
                    acc[mb][nb] = __builtin_amdgcn_mfma_f32_16x16x32_bf16(ah[mb], bh[nb], acc[mb][nb], 0, 0, 0);
                    acc[mb][nb] = __builtin_amdgcn_mfma_f32_16x16x32_bf16(ah[mb], bl[nb], acc[mb][nb], 0, 0, 0);
                    acc[mb][nb] = __builtin_amdgcn_mfma_f32_16x16x32_bf16(al[mb], bh[nb], acc[mb][nb], 0, 0, 0);
                }
        }
        __syncthreads();
    }

    // epilogue: + bias, store f32
    #pragma unroll
    for (int mb = 0; mb < 4; ++mb) {
        #pragma unroll
        for (int nb = 0; nb < 4; ++nb) {
            int col = n0 + nq + nb * 16 + lr;
            float bias = bc[col];
            #pragma unroll
            for (int r = 0; r < 4; ++r) {
                int row = m0 + mq + mb * 16 + lc * 4 + r;
                xg[(size_t)row * G4 + col] = acc[mb][nb][r] + bias;
            }
        }
    }
}

// ---------------------------------------------------------------------------
// One LSTM time step per kernel launch (R6, unchanged). The launch boundary
// is the grid barrier: stream-ordered kernels see each other's writes, so
// h_pk uses plain loads/stores — no atomics, no fences, no spinning.
// 64 WGs x 256 thr; WG g owns gate cols [g*32,g*32+32); wave w owns
// K-quarter [w*128,(w+1)*128). c and running h-sum live in global fp32.
// ---------------------------------------------------------------------------
__global__ __launch_bounds__(256) void lstm_step(
        const unsigned short* __restrict__ whh_hi, const unsigned short* __restrict__ whh_lo,
        const float* __restrict__ xg,
        const float* __restrict__ mask_h, const float* __restrict__ mask_c,
        unsigned int* __restrict__ h_pk,
        float* __restrict__ c_state, float* __restrict__ h_sum,
        int t) {
    __shared__ float red[4][64][32];        // 32 KB: per-wave K-partials

    int g = blockIdx.x, tid = threadIdx.x;
    int w = tid >> 6, l = tid & 63;
    int lr = l & 15, lc = l >> 4;
    int cur = (t & 1) * (BATCH * HDIM);
    int nxt = ((t + 1) & 1) * (BATCH * HDIM);

    // B fragments (Whh'' slice) — L2-resident after step 0 (same 64 KB/WG)
    bf16x8 bh[2][4], bl[2][4];
    #pragma unroll
    for (int nb = 0; nb < 2; ++nb)
        #pragma unroll
        for (int ks = 0; ks < 4; ++ks) {
            int n = g * 32 + nb * 16 + lr;
            int k = w * 128 + ks * 32 + lc * 8;
            bh[nb][ks] = *(const bf16x8*)(whh_hi + (size_t)n * HDIM + k);
            bl[nb][ks] = *(const bf16x8*)(whh_lo + (size_t)n * HDIM + k);
        }

    f32x4 acc[4][2] = {};
    #pragma unroll
    for (int ks = 0; ks < 4; ++ks) {
        int k = w * 128 + ks * 32 + lc * 8;
        #pragma unroll
        for (int mb = 0; mb < 4; ++mb) {
            int row = mb * 16 + lr;
            const unsigned long long* pq = (const unsigned long long*)(h_pk + cur + row * HDIM + k);
            unsigned long long q0 = pq[0], q1 = pq[1], q2 = pq[2], q3 = pq[3];
            union { unsigned int d[4]; bf16x8 v; } ahu, alu;
            {
                unsigned p0 = (unsigned)q0, p1 = (unsigned)(q0 >> 32);
                ahu.d[0] = __builtin_amdgcn_perm(p1, p0, 0x05040100u);
                alu.d[0] = __builtin_amdgcn_perm(p1, p0, 0x07060302u);
            }
            {
                unsigned p0 = (unsigned)q1, p1 = (unsigned)(q1 >> 32);
                ahu.d[1] = __builtin_amdgcn_perm(p1, p0, 0x05040100u);
                alu.d[1] = __builtin_amdgcn_perm(p1, p0, 0x07060302u);
            }
            {
                unsigned p0 = (unsigned)q2, p1 = (unsigned)(q2 >> 32);
                ahu.d[2] = __builtin_amdgcn_perm(p1, p0, 0x05040100u);
                alu.d[2] = __builtin_amdgcn_perm(p1, p0, 0x07060302u);
            }
            {
                unsigned p0 = (unsigned)q3, p1 = (unsigned)(q3 >> 32);
                ahu.d[3] = __builtin_amdgcn_perm(p1, p0, 0x05040100u);
                alu.d[3] = __builtin_amdgcn_perm(p1, p0, 0x07060302u);
            }
            bf16x8 ah = ahu.v, al = alu.v;
            #pragma unroll
            for (int nb = 0; nb < 2; ++nb) {
                acc[mb][nb] = __builtin_amdgcn_mfma_f32_16x16x32_bf16(ah, bh[nb][ks], acc[mb][nb], 0, 0, 0);
                acc[mb][nb] = __builtin_amdgcn_mfma_f32_16x16x32_bf16(ah, bl[nb][ks], acc[mb][nb], 0, 0, 0);
                acc[mb][nb] = __builtin_amdgcn_mfma_f32_16x16x32_bf16(al, bh[nb][ks], acc[mb][nb], 0, 0, 0);
            }
        }
    }
    #pragma unroll
    for (int mb = 0; mb < 4; ++mb)
        #pragma unroll
        for (int nb = 0; nb < 2; ++nb)
            #pragma unroll
            for (int r = 0; r < 4; ++r)
                red[w][mb * 16 + lc * 4 + r][nb * 16 + lr] = acc[mb][nb][r];
    __syncthreads();

    // cell phase: 2 cells per thread
    int b0_ = tid >> 3, jl0 = tid & 7, jg0 = g * 8 + jl0;
    int b1_ = (tid + 256) >> 3, jl1 = tid & 7, jg1 = g * 8 + jl1;
    #pragma unroll
    for (int e = 0; e < 2; ++e) {
        int b  = e ? b1_ : b0_;
        int jl = e ? jl1 : jl0;
        int jg = e ? jg1 : jg0;
        int nb4 = jl * 4;
        float gi = red[0][b][nb4 + 0] + red[1][b][nb4 + 0] + red[2][b][nb4 + 0] + red[3][b][nb4 + 0];
        float gf = red[0][b][nb4 + 1] + red[1][b][nb4 + 1] + red[2][b][nb4 + 1] + red[3][b][nb4 + 1];
        float gg = red[0][b][nb4 + 2] + red[1][b][nb4 + 2] + red[2][b][nb4 + 2] + red[3][b][nb4 + 2];
        float go = red[0][b][nb4 + 3] + red[1][b][nb4 + 3] + red[2][b][nb4 + 3] + red[3][b][nb4 + 3];
        const float4 xgv = *(const float4*)(xg + (size_t)(t * BATCH + b) * G4 + g * 32 + nb4);
        gi += xgv.x; gf += xgv.y; gg += xgv.z; go += xgv.w;
        size_t sidx = (size_t)b * HDIM + jg;
        size_t midx = (size_t)(t * BATCH + b) * HDIM + jg;
        float c_reg = c_state[sidx];
        float i_s = sigm_fast(gi);
        float f_s = sigm_fast(gf);
        float o_s = sigm_fast(go);
        float c_new = f_s * c_reg + i_s * tanh_fast(gg);
        float h_new = o_s * tanh_fast(c_new);
        h_new *= mask_h[midx];
        c_new *= mask_c[midx];
        c_state[sidx] = c_new;
        h_sum[sidx] += h_new;
        unsigned short hh = f2bf(h_new);
        unsigned short hl = f2bf(h_new - bf2f(hh));
        h_pk[nxt + sidx] = (unsigned)hh | ((unsigned)hl << 16);
    }
}

// ---------------------------------------------------------------------------
// Projection: WG g handles batch b = g -> out[g*11 + cl]
// ---------------------------------------------------------------------------
__global__ __launch_bounds__(256) void proj_kernel(
        const float* __restrict__ h_sum,
        const float* __restrict__ W_out, const float* __restrict__ b_out,
        float* __restrict__ out) {
    __shared__ float rbuf[NCLS * 256];
    int g = blockIdx.x, tid = threadIdx.x;
    float part[NCLS];
    #pragma unroll
    for (int cl = 0; cl < NCLS; ++cl) part[cl] = 0.f;
    for (int j = tid; j < HDIM; j += 256) {
        float hv = h_sum[g * HDIM + j] * (1.f / T_STEPS);
        #pragma unroll
        for (int cl = 0; cl < NCLS; ++cl)
            part[cl] += hv * W_out[cl * HDIM + j];
    }
    #pragma unroll
    for (int cl = 0; cl < NCLS; ++cl) rbuf[cl * 256 + tid] = part[cl];
    __syncthreads();
    if (tid < NCLS) {
        float s = b_out[tid];
        for (int i = 0; i < 256; ++i) s += rbuf[tid * 256 + i];
        out[g * NCLS + tid] = s;
    }
}

// ---------------------------------------------------------------------------
extern "C" void kernel_launch(void* const* d_in, const int* in_sizes, int n_in,
                              void* d_out, int out_size, void* d_ws, size_t ws_size,
                              hipStream_t stream) {
    const float* x      = (const float*)d_in[0];
    const float* h0     = (const float*)d_in[1];
    const float* c0     = (const float*)d_in[2];
    const float* W_ih   = (const float*)d_in[3];
    const float* W_hh   = (const float*)d_in[4];
    const float* b_ih   = (const float*)d_in[5];
    const float* b_hh   = (const float*)d_in[6];
    const float* W_out  = (const float*)d_in[7];
    const float* b_out  = (const float*)d_in[8];
    const float* mask_h = (const float*)d_in[9];
    const float* mask_c = (const float*)d_in[10];
    float* out = (float*)d_out;

    char* ws = (char*)d_ws;
    float*          xg      = (float*)(ws + 0);                  // 67,108,864 B
    unsigned short* wih_hi  = (unsigned short*)(ws + 67108864);  // 8,388,608
    unsigned short* wih_lo  = (unsigned short*)(ws + 75497472);  // 8,388,608
    unsigned short* whh_hi  = (unsigned short*)(ws + 83886080);  // 2,097,152
    unsigned short* whh_lo  = (unsigned short*)(ws + 85983232);  // 2,097,152
    float*          bc      = (float*)(ws + 88080384);           // 8,192
    unsigned int*   h_pk    = (unsigned int*)(ws + 88088576);    // 262,144 (2 bufs)
    float*          c_state = (float*)(ws + 88350720);           // 131,072
    float*          h_sum   = (float*)(ws + 88481792);           // 131,072

    prep_kernel<<<8192, 256, 0, stream>>>(W_ih, W_hh, b_ih, b_hh, h0, c0,
                                          wih_hi, wih_lo, whh_hi, whh_lo, bc,
                                          h_pk, c_state, h_sum);
    gemm_xg<<<1024, 256, 0, stream>>>(x, wih_hi, wih_lo, bc, xg);

    for (int t = 0; t < T_STEPS; ++t)
        lstm_step<<<64, 256, 0, stream>>>(whh_hi, whh_lo, xg, mask_h, mask_c,
                                          h_pk, c_state, h_sum, t);

    proj_kernel<<<64, 256, 0, stream>>>(h_sum, W_out, b_out, out);
}

// Round 11
// 1365.667 us; speedup vs baseline: 2.4633x; 1.1263x over previous
//
#include <hip/hip_runtime.h>
#include <cstdint>

#define T_STEPS 128
#define BATCH 64
#define IDIM 2048
#define HDIM 512
#define G4 2048   // 4*H
#define NCLS 11

typedef __attribute__((ext_vector_type(8))) short bf16x8;
typedef __attribute__((ext_vector_type(4))) float f32x4;

__device__ __forceinline__ unsigned short f2bf(float f) {
    unsigned int u = __builtin_bit_cast(unsigned int, f);
    unsigned int r = u + 0x7FFFu + ((u >> 16) & 1u);   // RNE
    return (unsigned short)(r >> 16);
}
__device__ __forceinline__ float bf2f(unsigned short b) {
    unsigned int u = ((unsigned int)b) << 16;
    return __builtin_bit_cast(float, u);
}
__device__ __forceinline__ float sigm_fast(float x) {
    return 1.f / (1.f + __expf(-x));
}
__device__ __forceinline__ float tanh_fast(float x) {
    float e = __expf(2.f * x);        // inf-safe: x>>0 -> 1, x<<0 -> -1
    return 1.f - 2.f / (e + 1.f);
}

// async global->LDS DMA, 16B per lane (dest = wave-uniform base + lane*16)
__device__ __forceinline__ void gload_lds16(const void* g, void* lds) {
    __builtin_amdgcn_global_load_lds(
        (const __attribute__((address_space(1))) unsigned int*)g,
        (__attribute__((address_space(3))) unsigned int*)lds, 16, 0, 0);
}

// ---------------------------------------------------------------------------
// Prep: permute gate rows to interleaved order (n' = 4*j + gate), split
// weights into bf16 hi/lo (RNE), combine biases, pack h0 into h_pk buffer 0
// (u32 = hi | lo<<16), copy c0 to c_state, zero h_sum.
// orig_row(n') = (n'&3)*512 + (n'>>2)
// ---------------------------------------------------------------------------
__global__ void prep_kernel(const float* __restrict__ W_ih, const float* __restrict__ W_hh,
                            const float* __restrict__ b_ih, const float* __restrict__ b_hh,
                            const float* __restrict__ h0, const float* __restrict__ c0,
                            unsigned short* __restrict__ wih_hi, unsigned short* __restrict__ wih_lo,
                            unsigned short* __restrict__ whh_hi, unsigned short* __restrict__ whh_lo,
                            float* __restrict__ bc,
                            unsigned int* __restrict__ h_pk,
                            float* __restrict__ c_state, float* __restrict__ h_sum) {
    int idx = blockIdx.x * blockDim.x + threadIdx.x;
    int stride = gridDim.x * blockDim.x;
    for (int i = idx; i < G4 * IDIM; i += stride) {
        int np = i / IDIM, k = i - np * IDIM;
        int orig = (np & 3) * HDIM + (np >> 2);
        float f = W_ih[(size_t)orig * IDIM + k];
        unsigned short hi = f2bf(f);
        wih_hi[i] = hi;
        wih_lo[i] = f2bf(f - bf2f(hi));
    }
    for (int i = idx; i < G4 * HDIM; i += stride) {
        int np = i / HDIM, k = i - np * HDIM;
        int orig = (np & 3) * HDIM + (np >> 2);
        float f = W_hh[(size_t)orig * HDIM + k];
        unsigned short hi = f2bf(f);
        whh_hi[i] = hi;
        whh_lo[i] = f2bf(f - bf2f(hi));
    }
    for (int i = idx; i < G4; i += stride) {
        int orig = (i & 3) * HDIM + (i >> 2);
        bc[i] = b_ih[orig] + b_hh[orig];
    }
    for (int i = idx; i < BATCH * HDIM; i += stride) {
        float f = h0[i];
        unsigned short hi = f2bf(f);
        unsigned short lo = f2bf(f - bf2f(hi));
        h_pk[i] = (unsigned)hi | ((unsigned)lo << 16);   // buffer 0
        c_state[i] = c0[i];
        h_sum[i] = 0.f;
    }
}

// ---------------------------------------------------------------------------
// x split: xs_hi = top16(x) (trunc), xs_lo = top16(x - hi) (exact residual,
// truncated). Same numerics as R10's in-gemm split (absmax 3.8e-6), done ONCE
// instead of 16x redundantly per N-block.
// ---------------------------------------------------------------------------
__global__ void prep_xsplit(const float* __restrict__ x,
                            unsigned short* __restrict__ xs_hi,
                            unsigned short* __restrict__ xs_lo) {
    int idx = blockIdx.x * blockDim.x + threadIdx.x;
    int stride = gridDim.x * blockDim.x;
    int n4 = (T_STEPS * BATCH * IDIM) / 4;
    for (int i = idx; i < n4; i += stride) {
        const float4 v = ((const float4*)x)[i];
        unsigned ux = __builtin_bit_cast(unsigned, v.x);
        unsigned uy = __builtin_bit_cast(unsigned, v.y);
        unsigned uz = __builtin_bit_cast(unsigned, v.z);
        unsigned uw = __builtin_bit_cast(unsigned, v.w);
        float rx = v.x - __builtin_bit_cast(float, ux & 0xFFFF0000u);
        float ry = v.y - __builtin_bit_cast(float, uy & 0xFFFF0000u);
        float rz = v.z - __builtin_bit_cast(float, uz & 0xFFFF0000u);
        float rw = v.w - __builtin_bit_cast(float, uw & 0xFFFF0000u);
        uint2 hw, lw;
        hw.x = __builtin_amdgcn_perm(uy, ux, 0x07060302u);
        hw.y = __builtin_amdgcn_perm(uw, uz, 0x07060302u);
        lw.x = __builtin_amdgcn_perm(__builtin_bit_cast(unsigned, ry),
                                     __builtin_bit_cast(unsigned, rx), 0x07060302u);
        lw.y = __builtin_amdgcn_perm(__builtin_bit_cast(unsigned, rw),
                                     __builtin_bit_cast(unsigned, rz), 0x07060302u);
        ((uint2*)xs_hi)[i] = hw;
        ((uint2*)xs_lo)[i] = lw;
    }
}

// ---------------------------------------------------------------------------
// xg GEMM v2: all-bf16 inputs, staging via global_load_lds (16B) with
// PRE-SWIZZLED global source (linear DMA dest + swizzled read = rule #21).
// LDS layout: [128][64] bf16, 16B unit u at row r holds global chunk u^(r&7).
// DMA chunk geometry: 1KB chunk ch covers rows ch*8..ch*8+7; lane l writes
// row ch*8+(l>>3), unit l&7 -> global chunk (l&7)^(l>>3).
// ---------------------------------------------------------------------------
__global__ __launch_bounds__(256) void gemm_xg_v2(
        const unsigned short* __restrict__ xs_hi, const unsigned short* __restrict__ xs_lo,
        const unsigned short* __restrict__ wih_hi, const unsigned short* __restrict__ wih_lo,
        const float* __restrict__ bc, float* __restrict__ xg) {
    __shared__ unsigned short As_hi[128][64];
    __shared__ unsigned short As_lo[128][64];
    __shared__ unsigned short Bs_hi[128][64];
    __shared__ unsigned short Bs_lo[128][64];

    int tid = threadIdx.x;
    int w = tid >> 6, l = tid & 63;
    int lr = l & 15, lc = l >> 4;
    int bid = blockIdx.x;
    int mt = bid & 63, nt = bid >> 6;       // 64 M-tiles x 16 N-tiles
    int m0 = mt * 128, n0 = nt * 128;
    int mq = (w >> 1) * 64, nq = (w & 1) * 64;

    int rowin = l >> 3;                     // 0..7: row within 8-row chunk
    int swch  = (l & 7) ^ rowin;            // pre-swizzled global 16B-chunk idx

    f32x4 acc[4][4] = {};

    for (int k0 = 0; k0 < IDIM; k0 += 64) {
        // stage 64KB via 16 gload_lds per wave (4 chunks x 4 arrays)
        #pragma unroll
        for (int c = 0; c < 4; ++c) {
            int ch = w * 4 + c;             // 1KB LDS chunk 0..15
            int r  = ch * 8 + rowin;        // tile row 0..127
            size_t ga = (size_t)(m0 + r) * IDIM + k0 + swch * 8;
            size_t gb = (size_t)(n0 + r) * IDIM + k0 + swch * 8;
            gload_lds16(xs_hi + ga,  (char*)As_hi + ch * 1024);
            gload_lds16(xs_lo + ga,  (char*)As_lo + ch * 1024);
            gload_lds16(wih_hi + gb, (char*)Bs_hi + ch * 1024);
            gload_lds16(wih_lo + gb, (char*)Bs_lo + ch * 1024);
        }
        __syncthreads();

        #pragma unroll
        for (int ks = 0; ks < 2; ++ks) {
            bf16x8 ah[4], al[4], bh[4], bl[4];
            int u0 = ks * 4 + lc;           // logical 16B unit 0..7
            #pragma unroll
            for (int mb = 0; mb < 4; ++mb) {
                int row = mq + mb * 16 + lr;
                int off = (u0 ^ (row & 7)) * 16;
                ah[mb] = *(const bf16x8*)((const char*)&As_hi[row][0] + off);
                al[mb] = *(const bf16x8*)((const char*)&As_lo[row][0] + off);
            }
            #pragma unroll
            for (int nb = 0; nb < 4; ++nb) {
                int row = nq + nb * 16 + lr;
                int off = (u0 ^ (row & 7)) * 16;
                bh[nb] = *(const bf16x8*)((const char*)&Bs_hi[row][0] + off);
                bl[nb] = *(const bf16x8*)((const char*)&Bs_lo[row][0] + off);
            }
            #pragma unroll
            for (int mb = 0; mb < 4; ++mb)
                #pragma unroll
                for (int nb = 0; nb < 4; ++nb) {
                    acc[mb][nb] = __builtin_amdgcn_mfma_f32_16x16x32_bf16(ah[mb], bh[nb], acc[mb][nb], 0, 0, 0);
                    acc[mb][nb] = __builtin_amdgcn_mfma_f32_16x16x32_bf16(ah[mb], bl[nb], acc[mb][nb], 0, 0, 0);
                    acc[mb][nb] = __builtin_amdgcn_mfma_f32_16x16x32_bf16(al[mb], bh[nb], acc[mb][nb], 0, 0, 0);
                }
        }
        __syncthreads();
    }

    #pragma unroll
    for (int mb = 0; mb < 4; ++mb) {
        #pragma unroll
        for (int nb = 0; nb < 4; ++nb) {
            int col = n0 + nq + nb * 16 + lr;
            float bias = bc[col];
            #pragma unroll
            for (int r = 0; r < 4; ++r) {
                int row = m0 + mq + mb * 16 + lc * 4 + r;
                xg[(size_t)row * G4 + col] = acc[mb][nb][r] + bias;
            }
        }
    }
}

// ---------------------------------------------------------------------------
// xg GEMM v1 (R10, reg-staged trunc-split) — fallback if ws is too small.
// ---------------------------------------------------------------------------
__global__ __launch_bounds__(256) void gemm_xg(const float* __restrict__ x,
        const unsigned short* __restrict__ wih_hi, const unsigned short* __restrict__ wih_lo,
        const float* __restrict__ bc, float* __restrict__ xg) {
    __shared__ unsigned short As_hi[128][64];
    __shared__ unsigned short As_lo[128][64];
    __shared__ unsigned short Bs_hi[128][64];
    __shared__ unsigned short Bs_lo[128][64];

    int tid = threadIdx.x;
    int w = tid >> 6, l = tid & 63;
    int lr = l & 15, lc = l >> 4;
    int bid = blockIdx.x;
    int mt = bid & 63, nt = bid >> 6;
    int m0 = mt * 128, n0 = nt * 128;
    int mq = (w >> 1) * 64, nq = (w & 1) * 64;

    f32x4 acc[4][4] = {};

    for (int k0 = 0; k0 < IDIM; k0 += 64) {
        #pragma unroll
        for (int i = 0; i < 8; ++i) {
            int p = i * 256 + tid;
            int r = p >> 4, c4 = p & 15;
            const float4 v = *(const float4*)(x + (size_t)(m0 + r) * IDIM + k0 + c4 * 4);
            unsigned ux = __builtin_bit_cast(unsigned, v.x);
            unsigned uy = __builtin_bit_cast(unsigned, v.y);
            unsigned uz = __builtin_bit_cast(unsigned, v.z);
            unsigned uw = __builtin_bit_cast(unsigned, v.w);
            float rx = v.x - __builtin_bit_cast(float, ux & 0xFFFF0000u);
            float ry = v.y - __builtin_bit_cast(float, uy & 0xFFFF0000u);
            float rz = v.z - __builtin_bit_cast(float, uz & 0xFFFF0000u);
            float rw = v.w - __builtin_bit_cast(float, uw & 0xFFFF0000u);
            uint2 hw, lw;
            hw.x = __builtin_amdgcn_perm(uy, ux, 0x07060302u);
            hw.y = __builtin_amdgcn_perm(uw, uz, 0x07060302u);
            lw.x = __builtin_amdgcn_perm(__builtin_bit_cast(unsigned, ry),
                                         __builtin_bit_cast(unsigned, rx), 0x07060302u);
            lw.y = __builtin_amdgcn_perm(__builtin_bit_cast(unsigned, rw),
                                         __builtin_bit_cast(unsigned, rz), 0x07060302u);
            int off = (((c4 >> 1) ^ (r & 7)) * 16) + (c4 & 1) * 8;
            *(uint2*)((char*)&As_hi[r][0] + off) = hw;
            *(uint2*)((char*)&As_lo[r][0] + off) = lw;
        }
        #pragma unroll
        for (int i = 0; i < 4; ++i) {
            int q = i * 256 + tid;
            int n = q >> 3, c16 = q & 7;
            size_t goff = (size_t)(n0 + n) * IDIM + k0 + c16 * 8;
            int off = (c16 ^ (n & 7)) * 16;
            *(uint4*)((char*)&Bs_hi[n][0] + off) = *(const uint4*)(wih_hi + goff);
            *(uint4*)((char*)&Bs_lo[n][0] + off) = *(const uint4*)(wih_lo + goff);
        }
        __syncthreads();

        #pragma unroll
        for (int ks = 0; ks < 2; ++ks) {
            bf16x8 ah[4], al[4], bh[4], bl[4];
            int u0 = ks * 4 + lc;
            #pragma unroll
            for (int mb = 0; mb < 4; ++mb) {
                int row = mq + mb * 16 + lr;
                int off = (u0 ^ (row & 7)) * 16;
                ah[mb] = *(const bf16x8*)((const char*)&As_hi[row][0] + off);
                al[mb] = *(const bf16x8*)((const char*)&As_lo[row][0] + off);
            }
            #pragma unroll
            for (int nb = 0; nb < 4; ++nb) {
                int row = nq + nb * 16 + lr;
                int off = (u0 ^ (row & 7)) * 16;
                bh[nb] = *(const bf16x8*)((const char*)&Bs_hi[row][0] + off);
                bl[nb] = *(const bf16x8*)((const char*)&Bs_lo[row][0] + off);
            }
            #pragma unroll
            for (int mb = 0; mb < 4; ++mb)
                #pragma unroll
                for (int nb = 0; nb < 4; ++nb) {
                    acc[mb][nb] = __builtin_amdgcn_mfma_f32_16x16x32_bf16(ah[mb], bh[nb], acc[mb][nb], 0, 0, 0);
                    acc[mb][nb] = __builtin_amdgcn_mfma_f32_16x16x32_bf16(ah[mb], bl[nb], acc[mb][nb], 0, 0, 0);
                    acc[mb][nb] = __builtin_amdgcn_mfma_f32_16x16x32_bf16(al[mb], bh[nb], acc[mb][nb], 0, 0, 0);
                }
        }
        __syncthreads();
    }

    #pragma unroll
    for (int mb = 0; mb < 4; ++mb) {
        #pragma unroll
        for (int nb = 0; nb < 4; ++nb) {
            int col = n0 + nq + nb * 16 + lr;
            float bias = bc[col];
            #pragma unroll
            for (int r = 0; r < 4; ++r) {
                int row = m0 + mq + mb * 16 + lc * 4 + r;
                xg[(size_t)row * G4 + col] = acc[mb][nb][r] + bias;
            }
        }
    }
}

// ---------------------------------------------------------------------------
// One LSTM time step per kernel launch (R10 + hoisted operand prefetch).
// ---------------------------------------------------------------------------
__global__ __launch_bounds__(256) void lstm_step(
        const unsigned short* __restrict__ whh_hi, const unsigned short* __restrict__ whh_lo,
        const float* __restrict__ xg,
        const float* __restrict__ mask_h, const float* __restrict__ mask_c,
        unsigned int* __restrict__ h_pk,
        float* __restrict__ c_state, float* __restrict__ h_sum,
        int t) {
    __shared__ float red[4][64][32];        // 32 KB: per-wave K-partials

    int g = blockIdx.x, tid = threadIdx.x;
    int w = tid >> 6, l = tid & 63;
    int lr = l & 15, lc = l >> 4;
    int cur = (t & 1) * (BATCH * HDIM);
    int nxt = ((t + 1) & 1) * (BATCH * HDIM);

    // cell-phase identities + hoisted operand prefetch (hide HBM/IC latency)
    int b0_ = tid >> 3, jl0 = tid & 7, jg0 = g * 8 + jl0;
    int b1_ = (tid + 256) >> 3, jl1 = tid & 7, jg1 = g * 8 + jl1;
    float4 xgv0 = *(const float4*)(xg + (size_t)(t * BATCH + b0_) * G4 + g * 32 + jl0 * 4);
    float4 xgv1 = *(const float4*)(xg + (size_t)(t * BATCH + b1_) * G4 + g * 32 + jl1 * 4);
    size_t mi0 = (size_t)(t * BATCH + b0_) * HDIM + jg0;
    size_t mi1 = (size_t)(t * BATCH + b1_) * HDIM + jg1;
    float mh0 = mask_h[mi0], mc0 = mask_c[mi0];
    float mh1 = mask_h[mi1], mc1 = mask_c[mi1];
    float cr0 = c_state[(size_t)b0_ * HDIM + jg0];
    float cr1 = c_state[(size_t)b1_ * HDIM + jg1];

    // B fragments (Whh'' slice) — L2-resident across steps (same 64 KB/WG)
    bf16x8 bh[2][4], bl[2][4];
    #pragma unroll
    for (int nb = 0; nb < 2; ++nb)
        #pragma unroll
        for (int ks = 0; ks < 4; ++ks) {
            int n = g * 32 + nb * 16 + lr;
            int k = w * 128 + ks * 32 + lc * 8;
            bh[nb][ks] = *(const bf16x8*)(whh_hi + (size_t)n * HDIM + k);
            bl[nb][ks] = *(const bf16x8*)(whh_lo + (size_t)n * HDIM + k);
        }

    f32x4 acc[4][2] = {};
    #pragma unroll
    for (int ks = 0; ks < 4; ++ks) {
        int k = w * 128 + ks * 32 + lc * 8;
        #pragma unroll
        for (int mb = 0; mb < 4; ++mb) {
            int row = mb * 16 + lr;
            const unsigned long long* pq = (const unsigned long long*)(h_pk + cur + row * HDIM + k);
            unsigned long long q0 = pq[0], q1 = pq[1], q2 = pq[2], q3 = pq[3];
            union { unsigned int d[4]; bf16x8 v; } ahu, alu;
            {
                unsigned p0 = (unsigned)q0, p1 = (unsigned)(q0 >> 32);
                ahu.d[0] = __builtin_amdgcn_perm(p1, p0, 0x05040100u);
                alu.d[0] = __builtin_amdgcn_perm(p1, p0, 0x07060302u);
            }
            {
                unsigned p0 = (unsigned)q1, p1 = (unsigned)(q1 >> 32);
                ahu.d[1] = __builtin_amdgcn_perm(p1, p0, 0x05040100u);
                alu.d[1] = __builtin_amdgcn_perm(p1, p0, 0x07060302u);
            }
            {
                unsigned p0 = (unsigned)q2, p1 = (unsigned)(q2 >> 32);
                ahu.d[2] = __builtin_amdgcn_perm(p1, p0, 0x05040100u);
                alu.d[2] = __builtin_amdgcn_perm(p1, p0, 0x07060302u);
            }
            {
                unsigned p0 = (unsigned)q3, p1 = (unsigned)(q3 >> 32);
                ahu.d[3] = __builtin_amdgcn_perm(p1, p0, 0x05040100u);
                alu.d[3] = __builtin_amdgcn_perm(p1, p0, 0x07060302u);
            }
            bf16x8 ah = ahu.v, al = alu.v;
            #pragma unroll
            for (int nb = 0; nb < 2; ++nb) {
                acc[mb][nb] = __builtin_amdgcn_mfma_f32_16x16x32_bf16(ah, bh[nb][ks], acc[mb][nb], 0, 0, 0);
                acc[mb][nb] = __builtin_amdgcn_mfma_f32_16x16x32_bf16(ah, bl[nb][ks], acc[mb][nb], 0, 0, 0);
                acc[mb][nb] = __builtin_amdgcn_mfma_f32_16x16x32_bf16(al, bh[nb][ks], acc[mb][nb], 0, 0, 0);
            }
        }
    }
    #pragma unroll
    for (int mb = 0; mb < 4; ++mb)
        #pragma unroll
        for (int nb = 0; nb < 2; ++nb)
            #pragma unroll
            for (int r = 0; r < 4; ++r)
                red[w][mb * 16 + lc * 4 + r][nb * 16 + lr] = acc[mb][nb][r];
    __syncthreads();

    // cell phase: 2 cells per thread
    #pragma unroll
    for (int e = 0; e < 2; ++e) {
        int b  = e ? b1_ : b0_;
        int jl = e ? jl1 : jl0;
        int jg = e ? jg1 : jg0;
        int nb4 = jl * 4;
        float gi = red[0][b][nb4 + 0] + red[1][b][nb4 + 0] + red[2][b][nb4 + 0] + red[3][b][nb4 + 0];
        float gf = red[0][b][nb4 + 1] + red[1][b][nb4 + 1] + red[2][b][nb4 + 1] + red[3][b][nb4 + 1];
        float gg = red[0][b][nb4 + 2] + red[1][b][nb4 + 2] + red[2][b][nb4 + 2] + red[3][b][nb4 + 2];
        float go = red[0][b][nb4 + 3] + red[1][b][nb4 + 3] + red[2][b][nb4 + 3] + red[3][b][nb4 + 3];
        const float4 xgv = e ? xgv1 : xgv0;
        gi += xgv.x; gf += xgv.y; gg += xgv.z; go += xgv.w;
        size_t sidx = (size_t)b * HDIM + jg;
        float c_reg = e ? cr1 : cr0;
        float i_s = sigm_fast(gi);
        float f_s = sigm_fast(gf);
        float o_s = sigm_fast(go);
        float c_new = f_s * c_reg + i_s * tanh_fast(gg);
        float h_new = o_s * tanh_fast(c_new);
        h_new *= (e ? mh1 : mh0);
        c_new *= (e ? mc1 : mc0);
        c_state[sidx] = c_new;
        h_sum[sidx] += h_new;
        unsigned short hh = f2bf(h_new);
        unsigned short hl = f2bf(h_new - bf2f(hh));
        h_pk[nxt + sidx] = (unsigned)hh | ((unsigned)hl << 16);
    }
}

// ---------------------------------------------------------------------------
// Projection: WG g handles batch b = g -> out[g*11 + cl]
// ---------------------------------------------------------------------------
__global__ __launch_bounds__(256) void proj_kernel(
        const float* __restrict__ h_sum,
        const float* __restrict__ W_out, const float* __restrict__ b_out,
        float* __restrict__ out) {
    __shared__ float rbuf[NCLS * 256];
    int g = blockIdx.x, tid = threadIdx.x;
    float part[NCLS];
    #pragma unroll
    for (int cl = 0; cl < NCLS; ++cl) part[cl] = 0.f;
    for (int j = tid; j < HDIM; j += 256) {
        float hv = h_sum[g * HDIM + j] * (1.f / T_STEPS);
        #pragma unroll
        for (int cl = 0; cl < NCLS; ++cl)
            part[cl] += hv * W_out[cl * HDIM + j];
    }
    #pragma unroll
    for (int cl = 0; cl < NCLS; ++cl) rbuf[cl * 256 + tid] = part[cl];
    __syncthreads();
    if (tid < NCLS) {
        float s = b_out[tid];
        for (int i = 0; i < 256; ++i) s += rbuf[tid * 256 + i];
        out[g * NCLS + tid] = s;
    }
}

// ---------------------------------------------------------------------------
extern "C" void kernel_launch(void* const* d_in, const int* in_sizes, int n_in,
                              void* d_out, int out_size, void* d_ws, size_t ws_size,
                              hipStream_t stream) {
    const float* x      = (const float*)d_in[0];
    const float* h0     = (const float*)d_in[1];
    const float* c0     = (const float*)d_in[2];
    const float* W_ih   = (const float*)d_in[3];
    const float* W_hh   = (const float*)d_in[4];
    const float* b_ih   = (const float*)d_in[5];
    const float* b_hh   = (const float*)d_in[6];
    const float* W_out  = (const float*)d_in[7];
    const float* b_out  = (const float*)d_in[8];
    const float* mask_h = (const float*)d_in[9];
    const float* mask_c = (const float*)d_in[10];
    float* out = (float*)d_out;

    char* ws = (char*)d_ws;
    float*          xg      = (float*)(ws + 0);                  // 67,108,864 B
    unsigned short* wih_hi  = (unsigned short*)(ws + 67108864);  // 8,388,608
    unsigned short* wih_lo  = (unsigned short*)(ws + 75497472);  // 8,388,608
    unsigned short* whh_hi  = (unsigned short*)(ws + 83886080);  // 2,097,152
    unsigned short* whh_lo  = (unsigned short*)(ws + 85983232);  // 2,097,152
    float*          bc      = (float*)(ws + 88080384);           // 8,192
    unsigned int*   h_pk    = (unsigned int*)(ws + 88088576);    // 262,144 (2 bufs)
    float*          c_state = (float*)(ws + 88350720);           // 131,072
    float*          h_sum   = (float*)(ws + 88481792);           // 131,072
    unsigned short* xs_hi   = (unsigned short*)(ws + 88612864);  // 33,554,432
    unsigned short* xs_lo   = (unsigned short*)(ws + 122167296); // 33,554,432
    const size_t NEED_V2 = 155721728;

    prep_kernel<<<8192, 256, 0, stream>>>(W_ih, W_hh, b_ih, b_hh, h0, c0,
                                          wih_hi, wih_lo, whh_hi, whh_lo, bc,
                                          h_pk, c_state, h_sum);
    if (ws_size >= NEED_V2) {
        prep_xsplit<<<4096, 256, 0, stream>>>(x, xs_hi, xs_lo);
        gemm_xg_v2<<<1024, 256, 0, stream>>>(xs_hi, xs_lo, wih_hi, wih_lo, bc, xg);
    } else {
        gemm_xg<<<1024, 256, 0, stream>>>(x, wih_hi, wih_lo, bc, xg);
    }

    for (int t = 0; t < T_STEPS; ++t)
        lstm_step<<<64, 256, 0, stream>>>(whh_hi, whh_lo, xg, mask_h, mask_c,
                                          h_pk, c_state, h_sum, t);

    proj_kernel<<<64, 256, 0, stream>>>(h_sum, W_out, b_out, out);
}